// Round 1
// baseline (575.523 us; speedup 1.0000x reference)
//
#include <hip/hip_runtime.h>

// Problem constants from the reference
constexpr int B = 2, C = 2, D = 160, H = 192, W = 224;
constexpr int HW = H * W;            // 43008
constexpr int S  = D * HW;           // 6,881,280 spatial voxels per batch
constexpr int TOTAL = B * S;         // 13,762,560 threads

__global__ __launch_bounds__(256) void warp3d_kernel(
    const float* __restrict__ I,     // [B,C,D,H,W]
    const float* __restrict__ flow,  // [B,3,D,H,W]
    float* __restrict__ out)         // [B,C,D,H,W]
{
    int idx = blockIdx.x * blockDim.x + threadIdx.x;
    if (idx >= TOTAL) return;

    int b = idx / S;
    int s = idx - b * S;
    int d = s / HW;
    int rem = s - d * HW;
    int h = rem / W;
    int w = rem - h * W;

    const long fb = (long)b * 3 * S + s;
    float fx = flow[fb]         + (float)w;
    float fy = flow[fb + S]     + (float)h;
    float fz = flow[fb + 2 * S] + (float)d;

    int x0 = (int)floorf(fx);
    int y0 = (int)floorf(fy);
    int z0 = (int)floorf(fz);
    int x1 = min(max(x0 + 1, 0), W - 1);
    int y1 = min(max(y0 + 1, 0), H - 1);
    int z1 = min(max(z0 + 1, 0), D - 1);
    x0 = min(max(x0, 0), W - 1);
    y0 = min(max(y0, 0), H - 1);
    z0 = min(max(z0, 0), D - 1);

    // Weights use the CLAMPED upper corner (matches reference exactly)
    float dx = (float)x1 - fx;
    float dy = (float)y1 - fy;
    float dz = (float)z1 - fz;
    float ex = 1.0f - dx, ey = 1.0f - dy, ez = 1.0f - dz;

    float wa = dz * dx * dy;
    float wb = dz * dx * ey;
    float wc = dz * ex * dy;
    float wd = dz * ex * ey;
    float we = ez * dx * dy;
    float wf = ez * dx * ey;
    float wg = ez * ex * dy;
    float wh = ez * ex * ey;

    int oz0 = z0 * HW, oz1 = z1 * HW;
    int oy0 = y0 * W,  oy1 = y1 * W;

    long base = (long)b * C * S;
#pragma unroll
    for (int c = 0; c < C; ++c) {
        const float* __restrict__ Ip = I + base + (long)c * S;
        float va = Ip[oz0 + oy0 + x0];
        float vb = Ip[oz0 + oy1 + x0];
        float vc = Ip[oz0 + oy0 + x1];
        float vd = Ip[oz0 + oy1 + x1];
        float ve = Ip[oz1 + oy0 + x0];
        float vf = Ip[oz1 + oy1 + x0];
        float vg = Ip[oz1 + oy0 + x1];
        float vh = Ip[oz1 + oy1 + x1];
        out[base + (long)c * S + s] =
            wa * va + wb * vb + wc * vc + wd * vd +
            we * ve + wf * vf + wg * vg + wh * vh;
    }
}

extern "C" void kernel_launch(void* const* d_in, const int* in_sizes, int n_in,
                              void* d_out, int out_size, void* d_ws, size_t ws_size,
                              hipStream_t stream) {
    const float* I    = (const float*)d_in[0];
    const float* flow = (const float*)d_in[1];
    float* out = (float*)d_out;

    int block = 256;
    int grid = (TOTAL + block - 1) / block;
    warp3d_kernel<<<grid, block, 0, stream>>>(I, flow, out);
}

// Round 2
// 549.223 us; speedup vs baseline: 1.0479x; 1.0479x over previous
//
#include <hip/hip_runtime.h>

// Problem constants from the reference
constexpr int B = 2, C = 2, D = 160, H = 192, W = 224;
constexpr int HW = H * W;            // 43008
constexpr int S  = D * HW;           // 6,881,280 spatial voxels per batch
constexpr int TOTAL = B * S;         // 13,762,560

// ---------------------------------------------------------------------------
// Pass 1: channel-interleave I: ws[b][s] = {I[b][0][s], I[b][1][s]}
// Fully coalesced float4 reads and float4 writes. 4 voxels per thread.
// ---------------------------------------------------------------------------
__global__ __launch_bounds__(256) void interleave_kernel(
    const float* __restrict__ I, float* __restrict__ ws)
{
    long t = (long)blockIdx.x * blockDim.x + threadIdx.x;
    long s4 = t * 4;
    if (s4 >= (long)TOTAL) return;
    int  b = (int)(s4 / S);
    long s = s4 - (long)b * S;

    const float* Ib = I + (long)b * C * S;
    float4 a = *(const float4*)(Ib + s);        // channel 0, 4 voxels
    float4 c = *(const float4*)(Ib + S + s);    // channel 1, 4 voxels

    float* o = ws + ((long)b * S + s) * 2;      // 32B-aligned (s % 4 == 0)
    *(float4*)(o)     = make_float4(a.x, c.x, a.y, c.y);
    *(float4*)(o + 4) = make_float4(a.z, c.z, a.w, c.w);
}

// ---------------------------------------------------------------------------
// Pass 2: warp with float2 gathers from the interleaved buffer.
// 2 consecutive-w voxels per thread; all 16 gathers issued before use.
// ---------------------------------------------------------------------------
__global__ __launch_bounds__(256, 4) void warp3d_i2(
    const float2* __restrict__ ws,   // [B, S] channel-interleaved
    const float* __restrict__ flow,  // [B, 3, D, H, W]
    float* __restrict__ out)         // [B, C, D, H, W]
{
    constexpr int SP = S / 2;
    int p = blockIdx.x * blockDim.x + threadIdx.x;   // voxel-pair index
    if (p >= B * SP) return;

    int b  = p / SP;
    int sp = p - b * SP;
    int s  = sp * 2;
    int d  = s / HW;
    int rem = s - d * HW;
    int h  = rem / W;
    int w  = rem - h * W;

    const float* fl = flow + (long)b * 3 * S;
    float2 fxv = *(const float2*)(fl + s);
    float2 fyv = *(const float2*)(fl + S + s);
    float2 fzv = *(const float2*)(fl + 2 * S + s);

    int   addr[2][8];
    float wt[2][8];
#pragma unroll
    for (int v = 0; v < 2; ++v) {
        float fx = (v ? fxv.y : fxv.x) + (float)(w + v);
        float fy = (v ? fyv.y : fyv.x) + (float)h;
        float fz = (v ? fzv.y : fzv.x) + (float)d;

        int x0 = (int)floorf(fx);
        int y0 = (int)floorf(fy);
        int z0 = (int)floorf(fz);
        int x1 = min(max(x0 + 1, 0), W - 1);
        int y1 = min(max(y0 + 1, 0), H - 1);
        int z1 = min(max(z0 + 1, 0), D - 1);
        x0 = min(max(x0, 0), W - 1);
        y0 = min(max(y0, 0), H - 1);
        z0 = min(max(z0, 0), D - 1);

        // Weights use the CLAMPED upper corner (matches reference exactly)
        float dx = (float)x1 - fx;
        float dy = (float)y1 - fy;
        float dz = (float)z1 - fz;
        float ex = 1.0f - dx, ey = 1.0f - dy, ez = 1.0f - dz;

        wt[v][0] = dz * dx * dy;
        wt[v][1] = dz * dx * ey;
        wt[v][2] = dz * ex * dy;
        wt[v][3] = dz * ex * ey;
        wt[v][4] = ez * dx * dy;
        wt[v][5] = ez * dx * ey;
        wt[v][6] = ez * ex * dy;
        wt[v][7] = ez * ex * ey;

        int z0o = z0 * HW, z1o = z1 * HW;
        int y0o = y0 * W,  y1o = y1 * W;
        addr[v][0] = z0o + y0o + x0;
        addr[v][1] = z0o + y1o + x0;
        addr[v][2] = z0o + y0o + x1;
        addr[v][3] = z0o + y1o + x1;
        addr[v][4] = z1o + y0o + x0;
        addr[v][5] = z1o + y1o + x0;
        addr[v][6] = z1o + y0o + x1;
        addr[v][7] = z1o + y1o + x1;
    }

    const float2* Ibp = ws + (long)b * S;
    float2 vals[2][8];
#pragma unroll
    for (int v = 0; v < 2; ++v)
#pragma unroll
        for (int k = 0; k < 8; ++k)
            vals[v][k] = Ibp[addr[v][k]];

    float2 o0 = make_float2(0.f, 0.f);   // voxel 0: {c0, c1}
    float2 o1 = make_float2(0.f, 0.f);   // voxel 1: {c0, c1}
#pragma unroll
    for (int k = 0; k < 8; ++k) {
        o0.x += wt[0][k] * vals[0][k].x;
        o0.y += wt[0][k] * vals[0][k].y;
        o1.x += wt[1][k] * vals[1][k].x;
        o1.y += wt[1][k] * vals[1][k].y;
    }

    float* ob = out + (long)b * C * S + s;
    *(float2*)(ob)     = make_float2(o0.x, o1.x);   // channel 0, w and w+1
    *(float2*)(ob + S) = make_float2(o0.y, o1.y);   // channel 1
}

// ---------------------------------------------------------------------------
// Fallback (round-1 kernel) if d_ws is too small for the interleaved copy.
// ---------------------------------------------------------------------------
__global__ __launch_bounds__(256) void warp3d_direct(
    const float* __restrict__ I,
    const float* __restrict__ flow,
    float* __restrict__ out)
{
    int idx = blockIdx.x * blockDim.x + threadIdx.x;
    if (idx >= TOTAL) return;

    int b = idx / S;
    int s = idx - b * S;
    int d = s / HW;
    int rem = s - d * HW;
    int h = rem / W;
    int w = rem - h * W;

    const long fb = (long)b * 3 * S + s;
    float fx = flow[fb]         + (float)w;
    float fy = flow[fb + S]     + (float)h;
    float fz = flow[fb + 2 * S] + (float)d;

    int x0 = (int)floorf(fx);
    int y0 = (int)floorf(fy);
    int z0 = (int)floorf(fz);
    int x1 = min(max(x0 + 1, 0), W - 1);
    int y1 = min(max(y0 + 1, 0), H - 1);
    int z1 = min(max(z0 + 1, 0), D - 1);
    x0 = min(max(x0, 0), W - 1);
    y0 = min(max(y0, 0), H - 1);
    z0 = min(max(z0, 0), D - 1);

    float dx = (float)x1 - fx;
    float dy = (float)y1 - fy;
    float dz = (float)z1 - fz;
    float ex = 1.0f - dx, ey = 1.0f - dy, ez = 1.0f - dz;

    float wa = dz * dx * dy, wb = dz * dx * ey, wc = dz * ex * dy, wd = dz * ex * ey;
    float we = ez * dx * dy, wf = ez * dx * ey, wg = ez * ex * dy, wh = ez * ex * ey;

    int oz0 = z0 * HW, oz1 = z1 * HW;
    int oy0 = y0 * W,  oy1 = y1 * W;

    long base = (long)b * C * S;
#pragma unroll
    for (int c = 0; c < C; ++c) {
        const float* __restrict__ Ip = I + base + (long)c * S;
        float va = Ip[oz0 + oy0 + x0];
        float vb = Ip[oz0 + oy1 + x0];
        float vc = Ip[oz0 + oy0 + x1];
        float vd = Ip[oz0 + oy1 + x1];
        float ve = Ip[oz1 + oy0 + x0];
        float vf = Ip[oz1 + oy1 + x0];
        float vg = Ip[oz1 + oy0 + x1];
        float vh = Ip[oz1 + oy1 + x1];
        out[base + (long)c * S + s] =
            wa * va + wb * vb + wc * vc + wd * vd +
            we * ve + wf * vf + wg * vg + wh * vh;
    }
}

extern "C" void kernel_launch(void* const* d_in, const int* in_sizes, int n_in,
                              void* d_out, int out_size, void* d_ws, size_t ws_size,
                              hipStream_t stream) {
    const float* I    = (const float*)d_in[0];
    const float* flow = (const float*)d_in[1];
    float* out = (float*)d_out;

    const size_t ws_needed = (size_t)TOTAL * 2 * sizeof(float);  // ~110 MB

    if (ws_size >= ws_needed) {
        float* wsf = (float*)d_ws;
        {
            int n = TOTAL / 4;
            interleave_kernel<<<(n + 255) / 256, 256, 0, stream>>>(I, wsf);
        }
        {
            int n = TOTAL / 2;
            warp3d_i2<<<(n + 255) / 256, 256, 0, stream>>>(
                (const float2*)wsf, flow, out);
        }
    } else {
        int grid = (TOTAL + 255) / 256;
        warp3d_direct<<<grid, 256, 0, stream>>>(I, flow, out);
    }
}